// Round 11
// baseline (346.419 us; speedup 1.0000x reference)
//
#include <hip/hip_runtime.h>

typedef __bf16 bf16;
typedef bf16 bf16x8 __attribute__((ext_vector_type(8)));
typedef float floatx16 __attribute__((ext_vector_type(16)));

#define AS1 __attribute__((address_space(1)))
#define AS3 __attribute__((address_space(3)))

#define KTOT 26112   // A2/B2 leading dim: 48*512 spectral + 3*512 AR columns

// ---------------------------------------------------------------------------
// R9-proven tile engine: 128x128 block, 4 waves (2x2 of 64x64), BK=64,
// 32x32x16 bf16 MFMA. Staging: global_load_lds width=16, lane-contiguous LDS,
// XOR swizzle on the global column (4-iteration burst — replay-verified).
// ---------------------------------------------------------------------------
__device__ __forceinline__ void stage_tile(const bf16* g, int ld, bf16* lds, int tid) {
#pragma unroll
    for (int it = 0; it < 4; ++it) {
        int q    = it * 256 + tid;        // 0..1023
        int row  = q >> 3;
        int col8 = (q & 7) ^ (row & 7);
        __builtin_amdgcn_global_load_lds(
            (const AS1 void*)(g + (size_t)row * ld + col8 * 8),
            (AS3 void*)(lds + q * 8), 16, 0, 0);
    }
}

// A frag (M=32,K=16): m=lane&31, k=8*(lane>>5)+j. B symmetric. 4 K-steps/BK.
__device__ __forceinline__ void mfma_block(const bf16* lA, const bf16* lB,
                                           floatx16 acc[2][2], int lane, int wm, int wn) {
    const int lrow = lane & 31;
    const int lk   = lane >> 5;
#pragma unroll
    for (int s = 0; s < 4; ++s) {   // four K=16 steps per BK=64
        bf16x8 af[2], bfr[2];
        const int c8 = s * 2 + lk;
#pragma unroll
        for (int mi = 0; mi < 2; ++mi) {
            int r = wm * 64 + mi * 32 + lrow;
            af[mi] = *(const bf16x8*)(lA + r * 64 + ((c8 ^ (r & 7)) << 3));
        }
#pragma unroll
        for (int ni = 0; ni < 2; ++ni) {
            int r = wn * 64 + ni * 32 + lrow;
            bfr[ni] = *(const bf16x8*)(lB + r * 64 + ((c8 ^ (r & 7)) << 3));
        }
#pragma unroll
        for (int mi = 0; mi < 2; ++mi)
#pragma unroll
            for (int ni = 0; ni < 2; ++ni)
                acc[mi][ni] = __builtin_amdgcn_mfma_f32_32x32x16_bf16(
                    af[mi], bfr[ni], acc[mi][ni], 0, 0, 0);
    }
}

// C/D mapping for 32x32 (m74/m101): col=lane&31, row=(r&3)+8*(r>>2)+4*(lane>>5)
#define CD_ROW(r, lane) (((r) & 3) + 8 * ((r) >> 2) + 4 * ((lane) >> 5))

// ---------------------------------------------------------------------------
// prep1: only what conv needs — xT transpose (256 blocks) + Tb fill (768).
// ---------------------------------------------------------------------------
__global__ void prep1(const float* __restrict__ x, const float* __restrict__ phi,
                      bf16* __restrict__ xT, bf16* __restrict__ Tb) {
    __shared__ float smem[64 * 65];
    const int b = blockIdx.x, tid = threadIdx.x;
    if (b < 256) {
        // xT[d][t] = x[t][d], 64x64 LDS transpose tiles
        int tt = (b >> 3) * 64, dd = (b & 7) * 64;
#pragma unroll
        for (int it = 0; it < 16; ++it) {
            int q = it * 256 + tid;
            int r = q >> 6, cc = q & 63;
            smem[r * 65 + cc] = x[(size_t)(tt + r) * 512 + dd + cc];
        }
        __syncthreads();
#pragma unroll
        for (int it = 0; it < 16; ++it) {
            int q = it * 256 + tid;
            int r = q >> 6, cc = q & 63;
            xT[(size_t)(dd + r) * 2048 + tt + cc] = (bf16)smem[cc * 65 + r];
        }
    } else {
        // Tb fill, one block per (kv,m): Tb[kv][m][i][j] = phi_kv[m*128+i-j].
        int b3 = b - 256;               // 0..767
        int kv = b3 >> 4, m = b3 & 15;
        int k  = (kv >= 24) ? kv - 24 : kv;
        if (tid < 255) {
            int sh = m * 128 - 127 + tid;
            float f = 0.f;
            if (sh >= 0) {
                f = phi[sh * 24 + k];
                if (kv >= 24 && (sh & 1)) f = -f;
            }
            smem[tid] = f;
        }
        __syncthreads();
        bf16* Tp = Tb + (size_t)b3 * 16384;
#pragma unroll
        for (int it = 0; it < 8; ++it) {
            int q = it * 256 + tid;     // over 128 i x 16 j8
            int i = q >> 4, j8 = (q & 15) * 8;
            bf16x8 v;
#pragma unroll
            for (int jj = 0; jj < 8; ++jj)
                v[jj] = (bf16)smem[127 + i - (j8 + jj)];
            *(bf16x8*)(Tp + i * 128 + j8) = v;
        }
    }
}

// ---------------------------------------------------------------------------
// conv_fused: bid < 3072 -> R9 conv (U2 tile per (kf,a,dblk), a-descending
// LPT). bid >= 3072 -> prep work that only proj needs (B2 spectral transpose,
// A2-AR fill, B2-AR fill) appended to backfill conv's scheduling tail.
// ---------------------------------------------------------------------------
__global__ __launch_bounds__(256) void conv_fused(const bf16* __restrict__ Tb,
                                                  const bf16* __restrict__ xT,
                                                  bf16* __restrict__ A2,
                                                  const float* __restrict__ x,
                                                  const float* __restrict__ M,
                                                  const float* __restrict__ Mp,
                                                  const float* __restrict__ Mm,
                                                  bf16* __restrict__ B2) {
    __shared__ float4 raw4[2048];      // 32 KB, aliased per branch
    const int bid = blockIdx.x, tid = threadIdx.x;
    if (bid < 3072) {
        bf16* lA = (bf16*)raw4;
        bf16* lB = (bf16*)raw4 + 128 * 64;
        const int lane = tid & 63, wave = tid >> 6, wm = wave & 1, wn = wave >> 1;
        const int a    = 15 - (bid / 192);   // longest-first
        const int rem  = bid % 192;
        const int kf   = rem >> 2;
        const int dblk = rem & 3;

        floatx16 acc[2][2];
#pragma unroll
        for (int mi = 0; mi < 2; ++mi)
#pragma unroll
            for (int ni = 0; ni < 2; ++ni)
#pragma unroll
                for (int e = 0; e < 16; ++e) acc[mi][ni][e] = 0.f;

        for (int c = 0; c <= a; ++c) {
            const bf16* Ab = Tb + ((size_t)kf * 16 + (a - c)) * 16384;
            const bf16* Bb = xT + (size_t)(dblk * 128) * 2048 + c * 128;
#pragma unroll
            for (int kk = 0; kk < 128; kk += 64) {
                stage_tile(Ab + kk, 128, lA, tid);
                stage_tile(Bb + kk, 2048, lB, tid);
                __syncthreads();
                mfma_block(lA, lB, acc, lane, wm, wn);
                __syncthreads();
            }
        }
        bf16* Ob = A2 + (size_t)(a * 128) * KTOT + kf * 512 + dblk * 128;
#pragma unroll
        for (int mi = 0; mi < 2; ++mi)
#pragma unroll
            for (int ni = 0; ni < 2; ++ni)
#pragma unroll
                for (int r = 0; r < 16; ++r) {
                    int row = wm * 64 + mi * 32 + CD_ROW(r, lane);
                    int col = wn * 64 + ni * 32 + (lane & 31);
                    Ob[(size_t)row * KTOT + col] = (bf16)acc[mi][ni][r];
                }
    } else if (bid < 6144) {
        // B2[o][kv*512+d] = Mp/Mm[kv][d][o], 64x64 LDS transpose
        float* smem = (float*)raw4;
        int b2 = bid - 3072;
        int kv = b2 >> 6, rem = b2 & 63;
        int dt = (rem >> 3) * 64, ot = (rem & 7) * 64;
        const float* src = (kv < 24) ? (Mp + (size_t)kv * 262144)
                                     : (Mm + (size_t)(kv - 24) * 262144);
#pragma unroll
        for (int it = 0; it < 16; ++it) {
            int q = it * 256 + tid;
            int r = q >> 6, cc = q & 63;
            smem[r * 65 + cc] = src[(size_t)(dt + r) * 512 + ot + cc];
        }
        __syncthreads();
#pragma unroll
        for (int it = 0; it < 16; ++it) {
            int q = it * 256 + tid;
            int r = q >> 6, cc = q & 63;
            B2[(size_t)(ot + r) * KTOT + kv * 512 + dt + cc] = (bf16)smem[cc * 65 + r];
        }
    } else if (bid < 7680) {
        // A2 AR columns: A2[t][24576 + i*512 + d] = x[t-i][d]
        int idx8 = (bid - 6144) * 256 + tid;   // over 2048*192
        int t = idx8 / 192, q = idx8 % 192;
        int i = q >> 6, d8 = (q & 63) * 8;
        bf16x8 v;
        if (t - i >= 0) {
            const float* xp = x + (size_t)(t - i) * 512 + d8;
#pragma unroll
            for (int jj = 0; jj < 8; ++jj) v[jj] = (bf16)xp[jj];
        } else {
#pragma unroll
            for (int jj = 0; jj < 8; ++jj) v[jj] = (bf16)0.f;
        }
        *(bf16x8*)(A2 + (size_t)t * KTOT + 24576 + i * 512 + d8) = v;
    } else {
        // B2 AR columns: B2[o][24576 + i*512 + d] = M[o][d][i]
        float* smem = (float*)raw4;
        int o = bid - 7680;
        for (int q = tid; q < 1536; q += 256) smem[q] = M[(size_t)o * 1536 + q];
        __syncthreads();
        for (int q = tid; q < 1536; q += 256) {
            int i = q >> 9, d = q & 511;
            B2[(size_t)o * KTOT + 24576 + q] = (bf16)smem[d * 3 + i];
        }
    }
}

// ---------------------------------------------------------------------------
// Projection GEMM: out[t][o] = sum_K A2[t][K]*B2[o][K], K=26112 = 17 x 1536.
// K-split x17 -> grid (16,17,4) = 1088 blocks, all co-resident (5 blk/CU LDS
// cap), one round. Partials fp32 to P2[sp].
// ---------------------------------------------------------------------------
__global__ __launch_bounds__(256) void proj_gemm(const bf16* __restrict__ A2,
                                                 const bf16* __restrict__ B2,
                                                 float* __restrict__ P2) {
    __shared__ bf16 lA[128 * 64], lB[128 * 64];
    const int tid = threadIdx.x;
    const int lane = tid & 63, wave = tid >> 6, wm = wave & 1, wn = wave >> 1;
    const int bm = blockIdx.x, sp = blockIdx.y, bn = blockIdx.z;
    const bf16* Ab = A2 + (size_t)bm * 128 * KTOT + sp * 1536;
    const bf16* Bb = B2 + (size_t)bn * 128 * KTOT + sp * 1536;

    floatx16 acc[2][2];
#pragma unroll
    for (int mi = 0; mi < 2; ++mi)
#pragma unroll
        for (int ni = 0; ni < 2; ++ni)
#pragma unroll
            for (int e = 0; e < 16; ++e) acc[mi][ni][e] = 0.f;

    for (int kk = 0; kk < 1536; kk += 64) {
        stage_tile(Ab + kk, KTOT, lA, tid);
        stage_tile(Bb + kk, KTOT, lB, tid);
        __syncthreads();
        mfma_block(lA, lB, acc, lane, wm, wn);
        __syncthreads();
    }
    float* Pt = P2 + (size_t)sp * 1048576;
#pragma unroll
    for (int mi = 0; mi < 2; ++mi)
#pragma unroll
        for (int ni = 0; ni < 2; ++ni)
#pragma unroll
            for (int r = 0; r < 16; ++r) {
                int t = bm * 128 + wm * 64 + mi * 32 + CD_ROW(r, lane);
                int o = bn * 128 + wn * 64 + ni * 32 + (lane & 31);
                Pt[(size_t)t * 512 + o] = acc[mi][ni][r];
            }
}

// ---------------------------------------------------------------------------
// reduce: out = sum of 17 K-split partials
// ---------------------------------------------------------------------------
__global__ void reduce17(const float* __restrict__ P2, float* __restrict__ out) {
    int idx = blockIdx.x * 256 + threadIdx.x;   // over 2048*512
    if (idx >= 2048 * 512) return;
    float s = 0.f;
#pragma unroll
    for (int sp = 0; sp < 17; ++sp)
        s += P2[(size_t)sp * 1048576 + idx];
    out[idx] = s;
}

// ---------------------------------------------------------------------------
// Launch
// ---------------------------------------------------------------------------
extern "C" void kernel_launch(void* const* d_in, const int* in_sizes, int n_in,
                              void* d_out, int out_size, void* d_ws, size_t ws_size,
                              hipStream_t stream) {
    const float* x   = (const float*)d_in[0];
    const float* phi = (const float*)d_in[1];
    const float* M   = (const float*)d_in[2];
    const float* Mp  = (const float*)d_in[3];
    const float* Mm  = (const float*)d_in[4];
    float* out = (float*)d_out;
    char* ws = (char*)d_ws;

    // workspace layout (bytes)
    bf16*  Tb = (bf16*)(ws + 0);           //  25,165,824  [48 x 16 x 128 x 128]
    bf16*  xT = (bf16*)(ws + 25165824);    //   2,097,152
    bf16*  A2 = (bf16*)(ws + 27262976);    // 106,954,752  [2048 x 26112]
    bf16*  B2 = (bf16*)(ws + 134217728);   //  26,738,688  [ 512 x 26112]
    float* P2 = (float*)(ws + 160956416);  //  71,303,168  [17 x 2048 x 512]
                                           //  total 232,259,584

    prep1<<<1024, 256, 0, stream>>>(x, phi, xT, Tb);
    conv_fused<<<8192, 256, 0, stream>>>(Tb, xT, A2, x, M, Mp, Mm, B2);
    proj_gemm<<<dim3(16, 17, 4), 256, 0, stream>>>(A2, B2, P2);
    reduce17<<<4096, 256, 0, stream>>>(P2, out);
}

// Round 12
// 325.123 us; speedup vs baseline: 1.0655x; 1.0655x over previous
//
#include <hip/hip_runtime.h>

typedef __bf16 bf16;
typedef bf16 bf16x8 __attribute__((ext_vector_type(8)));
typedef float floatx16 __attribute__((ext_vector_type(16)));

#define AS1 __attribute__((address_space(1)))
#define AS3 __attribute__((address_space(3)))

#define KTOT 26112   // A2/B2 leading dim: 48*512 spectral + 3*512 AR columns

// Bank-quad swizzle: rows {x, x+8, x+16, x+24} map to distinct quads so the
// 32-row 32x32 fragment read is <=2-way per 16-lane phase (2-way is free).
#define SWZ(r) ((((r) >> 3) + (r)) & 7)

// ---------------------------------------------------------------------------
// Tile engine: 128x128 block, 4 waves (2x2 of 64x64), BK=64, 32x32x16 bf16
// MFMA. Staging: global_load_lds width=16, lane-contiguous LDS, SWZ swizzle
// applied to the GLOBAL column; fragment ds_read_b128 undoes it.
// ---------------------------------------------------------------------------
__device__ __forceinline__ void stage_tile(const bf16* g, int ld, bf16* lds, int tid) {
#pragma unroll
    for (int it = 0; it < 4; ++it) {
        int q    = it * 256 + tid;        // 0..1023
        int row  = q >> 3;
        int col8 = (q & 7) ^ SWZ(row);
        __builtin_amdgcn_global_load_lds(
            (const AS1 void*)(g + (size_t)row * ld + col8 * 8),
            (AS3 void*)(lds + q * 8), 16, 0, 0);
    }
}

// A frag (M=32,K=16): m=lane&31, k=8*(lane>>5)+j. B symmetric. 4 K-steps/BK.
__device__ __forceinline__ void mfma_block(const bf16* lA, const bf16* lB,
                                           floatx16 acc[2][2], int lane, int wm, int wn) {
    const int lrow = lane & 31;
    const int lk   = lane >> 5;
#pragma unroll
    for (int s = 0; s < 4; ++s) {   // four K=16 steps per BK=64
        bf16x8 af[2], bfr[2];
        const int c8 = s * 2 + lk;
#pragma unroll
        for (int mi = 0; mi < 2; ++mi) {
            int r = wm * 64 + mi * 32 + lrow;
            af[mi] = *(const bf16x8*)(lA + r * 64 + ((c8 ^ SWZ(r)) << 3));
        }
#pragma unroll
        for (int ni = 0; ni < 2; ++ni) {
            int r = wn * 64 + ni * 32 + lrow;
            bfr[ni] = *(const bf16x8*)(lB + r * 64 + ((c8 ^ SWZ(r)) << 3));
        }
#pragma unroll
        for (int mi = 0; mi < 2; ++mi)
#pragma unroll
            for (int ni = 0; ni < 2; ++ni)
                acc[mi][ni] = __builtin_amdgcn_mfma_f32_32x32x16_bf16(
                    af[mi], bfr[ni], acc[mi][ni], 0, 0, 0);
    }
}

// C/D mapping for 32x32 (m74/m101): col=lane&31, row=(r&3)+8*(r>>2)+4*(lane>>5)
#define CD_ROW(r, lane) (((r) & 3) + 8 * ((r) >> 2) + 4 * ((lane) >> 5))

// ---------------------------------------------------------------------------
// Conv phase: U2 tile per (kf, a, dblk). A = Tb[kf][a-c] (128x128 Toeplitz),
// B = xT rows d (2 MB total, L2-resident). C written bf16 straight into
// A2[t][kf*512 + dblk*128 + d]. Grid 3072, a-descending (LPT packing).
// ---------------------------------------------------------------------------
__global__ __launch_bounds__(256) void conv_gemm(const bf16* __restrict__ Tb,
                                                 const bf16* __restrict__ xT,
                                                 bf16* __restrict__ A2) {
    __shared__ bf16 lA[128 * 64], lB[128 * 64];
    const int tid = threadIdx.x;
    const int lane = tid & 63, wave = tid >> 6, wm = wave & 1, wn = wave >> 1;
    const int bid = blockIdx.x;
    const int a    = 15 - (bid / 192);      // longest-first
    const int rem  = bid % 192;
    const int kf   = rem >> 2;
    const int dblk = rem & 3;

    floatx16 acc[2][2];
#pragma unroll
    for (int mi = 0; mi < 2; ++mi)
#pragma unroll
        for (int ni = 0; ni < 2; ++ni)
#pragma unroll
            for (int e = 0; e < 16; ++e) acc[mi][ni][e] = 0.f;

    for (int c = 0; c <= a; ++c) {
        const bf16* Ab = Tb + ((size_t)kf * 16 + (a - c)) * 16384;
        const bf16* Bb = xT + (size_t)(dblk * 128) * 2048 + c * 128;
#pragma unroll
        for (int kk = 0; kk < 128; kk += 64) {
            stage_tile(Ab + kk, 128, lA, tid);
            stage_tile(Bb + kk, 2048, lB, tid);
            __syncthreads();
            mfma_block(lA, lB, acc, lane, wm, wn);
            __syncthreads();
        }
    }
    bf16* Ob = A2 + (size_t)(a * 128) * KTOT + kf * 512 + dblk * 128;
#pragma unroll
    for (int mi = 0; mi < 2; ++mi)
#pragma unroll
        for (int ni = 0; ni < 2; ++ni)
#pragma unroll
            for (int r = 0; r < 16; ++r) {
                int row = wm * 64 + mi * 32 + CD_ROW(r, lane);
                int col = wn * 64 + ni * 32 + (lane & 31);
                Ob[(size_t)row * KTOT + col] = (bf16)acc[mi][ni][r];
            }
}

// ---------------------------------------------------------------------------
// Projection GEMM: out[t][o] = sum_K A2[t][K]*B2[o][K], K=26112 = 17 x 1536.
// K-split x17 -> grid (16,17,4) = 1088 blocks, ~one 5-blocks/CU round.
// ---------------------------------------------------------------------------
__global__ __launch_bounds__(256) void proj_gemm(const bf16* __restrict__ A2,
                                                 const bf16* __restrict__ B2,
                                                 float* __restrict__ P2) {
    __shared__ bf16 lA[128 * 64], lB[128 * 64];
    const int tid = threadIdx.x;
    const int lane = tid & 63, wave = tid >> 6, wm = wave & 1, wn = wave >> 1;
    const int bm = blockIdx.x, sp = blockIdx.y, bn = blockIdx.z;
    const bf16* Ab = A2 + (size_t)bm * 128 * KTOT + sp * 1536;
    const bf16* Bb = B2 + (size_t)bn * 128 * KTOT + sp * 1536;

    floatx16 acc[2][2];
#pragma unroll
    for (int mi = 0; mi < 2; ++mi)
#pragma unroll
        for (int ni = 0; ni < 2; ++ni)
#pragma unroll
            for (int e = 0; e < 16; ++e) acc[mi][ni][e] = 0.f;

    for (int kk = 0; kk < 1536; kk += 64) {
        stage_tile(Ab + kk, KTOT, lA, tid);
        stage_tile(Bb + kk, KTOT, lB, tid);
        __syncthreads();
        mfma_block(lA, lB, acc, lane, wm, wn);
        __syncthreads();
    }
    float* Pt = P2 + (size_t)sp * 1048576;
#pragma unroll
    for (int mi = 0; mi < 2; ++mi)
#pragma unroll
        for (int ni = 0; ni < 2; ++ni)
#pragma unroll
            for (int r = 0; r < 16; ++r) {
                int t = bm * 128 + wm * 64 + mi * 32 + CD_ROW(r, lane);
                int o = bn * 128 + wn * 64 + ni * 32 + (lane & 31);
                Pt[(size_t)t * 512 + o] = acc[mi][ni][r];
            }
}

// ---------------------------------------------------------------------------
// Fused prep (R9 structure): xT transpose / A2-AR fill / B2 spectral
// transpose / B2-AR / Tb fill (LDS-staged phi)
// ---------------------------------------------------------------------------
__global__ void prep_all(const float* __restrict__ x, const float* __restrict__ phi,
                         const float* __restrict__ M, const float* __restrict__ Mp,
                         const float* __restrict__ Mm, bf16* __restrict__ xT,
                         bf16* __restrict__ A2, bf16* __restrict__ B2,
                         bf16* __restrict__ Tb) {
    __shared__ float smem[64 * 65];
    const int b = blockIdx.x, tid = threadIdx.x;
    if (b < 256) {
        // xT[d][t] = x[t][d], 64x64 LDS transpose tiles
        int tt = (b >> 3) * 64, dd = (b & 7) * 64;
#pragma unroll
        for (int it = 0; it < 16; ++it) {
            int q = it * 256 + tid;
            int r = q >> 6, cc = q & 63;
            smem[r * 65 + cc] = x[(size_t)(tt + r) * 512 + dd + cc];
        }
        __syncthreads();
#pragma unroll
        for (int it = 0; it < 16; ++it) {
            int q = it * 256 + tid;
            int r = q >> 6, cc = q & 63;
            xT[(size_t)(dd + r) * 2048 + tt + cc] = (bf16)smem[cc * 65 + r];
        }
    } else if (b < 1792) {
        // A2 AR columns: A2[t][24576 + i*512 + d] = x[t-i][d]
        int idx8 = (b - 256) * 256 + tid;   // over 2048*192
        int t = idx8 / 192, q = idx8 % 192;
        int i = q >> 6, d8 = (q & 63) * 8;
        bf16x8 v;
        if (t - i >= 0) {
            const float* xp = x + (size_t)(t - i) * 512 + d8;
#pragma unroll
            for (int jj = 0; jj < 8; ++jj) v[jj] = (bf16)xp[jj];
        } else {
#pragma unroll
            for (int jj = 0; jj < 8; ++jj) v[jj] = (bf16)0.f;
        }
        *(bf16x8*)(A2 + (size_t)t * KTOT + 24576 + i * 512 + d8) = v;
    } else if (b < 4864) {
        // B2[o][kv*512+d] = Mp/Mm[kv][d][o], 64x64 LDS transpose
        int b2 = b - 1792;
        int kv = b2 >> 6, rem = b2 & 63;
        int dt = (rem >> 3) * 64, ot = (rem & 7) * 64;
        const float* src = (kv < 24) ? (Mp + (size_t)kv * 262144)
                                     : (Mm + (size_t)(kv - 24) * 262144);
#pragma unroll
        for (int it = 0; it < 16; ++it) {
            int q = it * 256 + tid;
            int r = q >> 6, cc = q & 63;
            smem[r * 65 + cc] = src[(size_t)(dt + r) * 512 + ot + cc];
        }
        __syncthreads();
#pragma unroll
        for (int it = 0; it < 16; ++it) {
            int q = it * 256 + tid;
            int r = q >> 6, cc = q & 63;
            B2[(size_t)(ot + r) * KTOT + kv * 512 + dt + cc] = (bf16)smem[cc * 65 + r];
        }
    } else if (b < 5376) {
        // B2 AR columns: B2[o][24576 + i*512 + d] = M[o][d][i]
        int o = b - 4864;
        for (int q = tid; q < 1536; q += 256) smem[q] = M[(size_t)o * 1536 + q];
        __syncthreads();
        for (int q = tid; q < 1536; q += 256) {
            int i = q >> 9, d = q & 511;
            B2[(size_t)o * KTOT + 24576 + q] = (bf16)smem[d * 3 + i];
        }
    } else {
        // Tb fill, one block per (kv,m): Tb[kv][m][i][j] = phi_kv[m*128+i-j].
        int b3 = b - 5376;              // 0..767
        int kv = b3 >> 4, m = b3 & 15;
        int k  = (kv >= 24) ? kv - 24 : kv;
        if (tid < 255) {
            int sh = m * 128 - 127 + tid;
            float f = 0.f;
            if (sh >= 0) {
                f = phi[sh * 24 + k];
                if (kv >= 24 && (sh & 1)) f = -f;
            }
            smem[tid] = f;
        }
        __syncthreads();
        bf16* Tp = Tb + (size_t)b3 * 16384;
#pragma unroll
        for (int it = 0; it < 8; ++it) {
            int q = it * 256 + tid;     // over 128 i x 16 j8
            int i = q >> 4, j8 = (q & 15) * 8;
            bf16x8 v;
#pragma unroll
            for (int jj = 0; jj < 8; ++jj)
                v[jj] = (bf16)smem[127 + i - (j8 + jj)];
            *(bf16x8*)(Tp + i * 128 + j8) = v;
        }
    }
}

// ---------------------------------------------------------------------------
// reduce: out = sum of 17 K-split partials
// ---------------------------------------------------------------------------
__global__ void reduce17(const float* __restrict__ P2, float* __restrict__ out) {
    int idx = blockIdx.x * 256 + threadIdx.x;   // over 2048*512
    if (idx >= 2048 * 512) return;
    float s = 0.f;
#pragma unroll
    for (int sp = 0; sp < 17; ++sp)
        s += P2[(size_t)sp * 1048576 + idx];
    out[idx] = s;
}

// ---------------------------------------------------------------------------
// Launch
// ---------------------------------------------------------------------------
extern "C" void kernel_launch(void* const* d_in, const int* in_sizes, int n_in,
                              void* d_out, int out_size, void* d_ws, size_t ws_size,
                              hipStream_t stream) {
    const float* x   = (const float*)d_in[0];
    const float* phi = (const float*)d_in[1];
    const float* M   = (const float*)d_in[2];
    const float* Mp  = (const float*)d_in[3];
    const float* Mm  = (const float*)d_in[4];
    float* out = (float*)d_out;
    char* ws = (char*)d_ws;

    // workspace layout (bytes)
    bf16*  Tb = (bf16*)(ws + 0);           //  25,165,824  [48 x 16 x 128 x 128]
    bf16*  xT = (bf16*)(ws + 25165824);    //   2,097,152
    bf16*  A2 = (bf16*)(ws + 27262976);    // 106,954,752  [2048 x 26112]
    bf16*  B2 = (bf16*)(ws + 134217728);   //  26,738,688  [ 512 x 26112]
    float* P2 = (float*)(ws + 160956416);  //  71,303,168  [17 x 2048 x 512]
                                           //  total 232,259,584

    prep_all<<<6144, 256, 0, stream>>>(x, phi, M, Mp, Mm, xT, A2, B2, Tb);
    conv_gemm<<<3072, 256, 0, stream>>>(Tb, xT, A2);
    proj_gemm<<<dim3(16, 17, 4), 256, 0, stream>>>(A2, B2, P2);
    reduce17<<<4096, 256, 0, stream>>>(P2, out);
}

// Round 13
// 308.404 us; speedup vs baseline: 1.1233x; 1.0542x over previous
//
#include <hip/hip_runtime.h>

typedef __bf16 bf16;
typedef bf16 bf16x8 __attribute__((ext_vector_type(8)));
typedef float floatx16 __attribute__((ext_vector_type(16)));

#define AS1 __attribute__((address_space(1)))
#define AS3 __attribute__((address_space(3)))

#define KTOT 26112   // A2/B2 leading dim: 48*512 spectral + 3*512 AR columns

// ---------------------------------------------------------------------------
// R9-proven tile engine: 128x128 block, 4 waves (2x2 of 64x64), BK=64,
// 32x32x16 bf16 MFMA. Staging: global_load_lds width=16, lane-contiguous LDS,
// XOR swizzle on the global column. (The residual 4cyc/ds_read bank cost is
// structural to 32-row b128 reads — measured invariant under row permutation,
// R12 — and overlaps with the barrier drain at this occupancy.)
// ---------------------------------------------------------------------------
__device__ __forceinline__ void stage_tile(const bf16* g, int ld, bf16* lds, int tid) {
#pragma unroll
    for (int it = 0; it < 4; ++it) {
        int q    = it * 256 + tid;        // 0..1023
        int row  = q >> 3;
        int col8 = (q & 7) ^ (row & 7);
        __builtin_amdgcn_global_load_lds(
            (const AS1 void*)(g + (size_t)row * ld + col8 * 8),
            (AS3 void*)(lds + q * 8), 16, 0, 0);
    }
}

// A frag (M=32,K=16): m=lane&31, k=8*(lane>>5)+j. B symmetric. 4 K-steps/BK.
__device__ __forceinline__ void mfma_block(const bf16* lA, const bf16* lB,
                                           floatx16 acc[2][2], int lane, int wm, int wn) {
    const int lrow = lane & 31;
    const int lk   = lane >> 5;
#pragma unroll
    for (int s = 0; s < 4; ++s) {   // four K=16 steps per BK=64
        bf16x8 af[2], bfr[2];
        const int c8 = s * 2 + lk;
#pragma unroll
        for (int mi = 0; mi < 2; ++mi) {
            int r = wm * 64 + mi * 32 + lrow;
            af[mi] = *(const bf16x8*)(lA + r * 64 + ((c8 ^ (r & 7)) << 3));
        }
#pragma unroll
        for (int ni = 0; ni < 2; ++ni) {
            int r = wn * 64 + ni * 32 + lrow;
            bfr[ni] = *(const bf16x8*)(lB + r * 64 + ((c8 ^ (r & 7)) << 3));
        }
#pragma unroll
        for (int mi = 0; mi < 2; ++mi)
#pragma unroll
            for (int ni = 0; ni < 2; ++ni)
                acc[mi][ni] = __builtin_amdgcn_mfma_f32_32x32x16_bf16(
                    af[mi], bfr[ni], acc[mi][ni], 0, 0, 0);
    }
}

// C/D mapping for 32x32 (m74/m101): col=lane&31, row=(r&3)+8*(r>>2)+4*(lane>>5)
#define CD_ROW(r, lane) (((r) & 3) + 8 * ((r) >> 2) + 4 * ((lane) >> 5))

// ---------------------------------------------------------------------------
// Conv phase: U2 tile per (kf, a, dblk). A = Tb[kf][a-c] (128x128 Toeplitz),
// B = xT rows d (2 MB total, L2-resident). C written bf16 straight into
// A2[t][kf*512 + dblk*128 + d]. Grid 3072, a-descending (LPT packing).
// ---------------------------------------------------------------------------
__global__ __launch_bounds__(256) void conv_gemm(const bf16* __restrict__ Tb,
                                                 const bf16* __restrict__ xT,
                                                 bf16* __restrict__ A2) {
    __shared__ bf16 lA[128 * 64], lB[128 * 64];
    const int tid = threadIdx.x;
    const int lane = tid & 63, wave = tid >> 6, wm = wave & 1, wn = wave >> 1;
    const int bid = blockIdx.x;
    const int a    = 15 - (bid / 192);      // longest-first
    const int rem  = bid % 192;
    const int kf   = rem >> 2;
    const int dblk = rem & 3;

    floatx16 acc[2][2];
#pragma unroll
    for (int mi = 0; mi < 2; ++mi)
#pragma unroll
        for (int ni = 0; ni < 2; ++ni)
#pragma unroll
            for (int e = 0; e < 16; ++e) acc[mi][ni][e] = 0.f;

    for (int c = 0; c <= a; ++c) {
        const bf16* Ab = Tb + ((size_t)kf * 16 + (a - c)) * 16384;
        const bf16* Bb = xT + (size_t)(dblk * 128) * 2048 + c * 128;
#pragma unroll
        for (int kk = 0; kk < 128; kk += 64) {
            stage_tile(Ab + kk, 128, lA, tid);
            stage_tile(Bb + kk, 2048, lB, tid);
            __syncthreads();
            mfma_block(lA, lB, acc, lane, wm, wn);
            __syncthreads();
        }
    }
    bf16* Ob = A2 + (size_t)(a * 128) * KTOT + kf * 512 + dblk * 128;
#pragma unroll
    for (int mi = 0; mi < 2; ++mi)
#pragma unroll
        for (int ni = 0; ni < 2; ++ni)
#pragma unroll
            for (int r = 0; r < 16; ++r) {
                int row = wm * 64 + mi * 32 + CD_ROW(r, lane);
                int col = wn * 64 + ni * 32 + (lane & 31);
                Ob[(size_t)row * KTOT + col] = (bf16)acc[mi][ni][r];
            }
}

// ---------------------------------------------------------------------------
// Projection GEMM: out[t][o] = sum_K A2[t][K]*B2[o][K], K=26112 (408 BK).
// K-split x12 (K=2176 each) -> grid (16,12,4) = 768 = exactly 3 blocks/CU.
// Partials in bf16 (quant error ~1-2 absolute, threshold 61).
// ---------------------------------------------------------------------------
__global__ __launch_bounds__(256) void proj_gemm(const bf16* __restrict__ A2,
                                                 const bf16* __restrict__ B2,
                                                 bf16* __restrict__ P2) {
    __shared__ bf16 lA[128 * 64], lB[128 * 64];
    const int tid = threadIdx.x;
    const int lane = tid & 63, wave = tid >> 6, wm = wave & 1, wn = wave >> 1;
    const int bm = blockIdx.x, sp = blockIdx.y, bn = blockIdx.z;
    const bf16* Ab = A2 + (size_t)bm * 128 * KTOT + sp * 2176;
    const bf16* Bb = B2 + (size_t)bn * 128 * KTOT + sp * 2176;

    floatx16 acc[2][2];
#pragma unroll
    for (int mi = 0; mi < 2; ++mi)
#pragma unroll
        for (int ni = 0; ni < 2; ++ni)
#pragma unroll
            for (int e = 0; e < 16; ++e) acc[mi][ni][e] = 0.f;

    for (int kk = 0; kk < 2176; kk += 64) {
        stage_tile(Ab + kk, KTOT, lA, tid);
        stage_tile(Bb + kk, KTOT, lB, tid);
        __syncthreads();
        mfma_block(lA, lB, acc, lane, wm, wn);
        __syncthreads();
    }
    bf16* Pt = P2 + (size_t)sp * 1048576;
#pragma unroll
    for (int mi = 0; mi < 2; ++mi)
#pragma unroll
        for (int ni = 0; ni < 2; ++ni)
#pragma unroll
            for (int r = 0; r < 16; ++r) {
                int t = bm * 128 + wm * 64 + mi * 32 + CD_ROW(r, lane);
                int o = bn * 128 + wn * 64 + ni * 32 + (lane & 31);
                Pt[(size_t)t * 512 + o] = (bf16)acc[mi][ni][r];
            }
}

// ---------------------------------------------------------------------------
// Fused prep: xT transpose / A2-AR fill / B2 spectral transpose (vectorized
// bf16x8 stores) / B2-AR / Tb fill (LDS-staged phi)
// ---------------------------------------------------------------------------
__global__ void prep_all(const float* __restrict__ x, const float* __restrict__ phi,
                         const float* __restrict__ M, const float* __restrict__ Mp,
                         const float* __restrict__ Mm, bf16* __restrict__ xT,
                         bf16* __restrict__ A2, bf16* __restrict__ B2,
                         bf16* __restrict__ Tb) {
    __shared__ float smem[64 * 65];
    const int b = blockIdx.x, tid = threadIdx.x;
    if (b < 256) {
        // xT[d][t] = x[t][d], 64x64 LDS transpose tiles
        int tt = (b >> 3) * 64, dd = (b & 7) * 64;
#pragma unroll
        for (int it = 0; it < 16; ++it) {
            int q = it * 256 + tid;
            int r = q >> 6, cc = q & 63;
            smem[r * 65 + cc] = x[(size_t)(tt + r) * 512 + dd + cc];
        }
        __syncthreads();
#pragma unroll
        for (int it = 0; it < 16; ++it) {
            int q = it * 256 + tid;
            int r = q >> 6, cc = q & 63;
            xT[(size_t)(dd + r) * 2048 + tt + cc] = (bf16)smem[cc * 65 + r];
        }
    } else if (b < 1792) {
        // A2 AR columns: A2[t][24576 + i*512 + d] = x[t-i][d]
        int idx8 = (b - 256) * 256 + tid;   // over 2048*192
        int t = idx8 / 192, q = idx8 % 192;
        int i = q >> 6, d8 = (q & 63) * 8;
        bf16x8 v;
        if (t - i >= 0) {
            const float* xp = x + (size_t)(t - i) * 512 + d8;
#pragma unroll
            for (int jj = 0; jj < 8; ++jj) v[jj] = (bf16)xp[jj];
        } else {
#pragma unroll
            for (int jj = 0; jj < 8; ++jj) v[jj] = (bf16)0.f;
        }
        *(bf16x8*)(A2 + (size_t)t * KTOT + 24576 + i * 512 + d8) = v;
    } else if (b < 4864) {
        // B2[o][kv*512+d] = Mp/Mm[kv][d][o], 64x64 LDS transpose.
        // Store phase vectorized: bf16x8 per thread, 1 KB per wave-instr.
        int b2 = b - 1792;
        int kv = b2 >> 6, rem = b2 & 63;
        int dt = (rem >> 3) * 64, ot = (rem & 7) * 64;
        const float* src = (kv < 24) ? (Mp + (size_t)kv * 262144)
                                     : (Mm + (size_t)(kv - 24) * 262144);
#pragma unroll
        for (int it = 0; it < 16; ++it) {
            int q = it * 256 + tid;
            int r = q >> 6, cc = q & 63;   // r = d-local, cc = o-local
            smem[r * 65 + cc] = src[(size_t)(dt + r) * 512 + ot + cc];
        }
        __syncthreads();
#pragma unroll
        for (int it = 0; it < 2; ++it) {
            int q = it * 256 + tid;        // over 64 o x 8 d-chunks
            int o = q >> 3, d8 = (q & 7) * 8;
            bf16x8 v;
#pragma unroll
            for (int jj = 0; jj < 8; ++jj)
                v[jj] = (bf16)smem[(d8 + jj) * 65 + o];
            *(bf16x8*)(B2 + (size_t)(ot + o) * KTOT + kv * 512 + dt + d8) = v;
        }
    } else if (b < 5376) {
        // B2 AR columns: B2[o][24576 + i*512 + d] = M[o][d][i]
        int o = b - 4864;
        for (int q = tid; q < 1536; q += 256) smem[q] = M[(size_t)o * 1536 + q];
        __syncthreads();
        for (int q = tid; q < 1536; q += 256) {
            int i = q >> 9, d = q & 511;
            B2[(size_t)o * KTOT + 24576 + q] = (bf16)smem[d * 3 + i];
        }
    } else {
        // Tb fill, one block per (kv,m): Tb[kv][m][i][j] = phi_kv[m*128+i-j].
        int b3 = b - 5376;              // 0..767
        int kv = b3 >> 4, m = b3 & 15;
        int k  = (kv >= 24) ? kv - 24 : kv;
        if (tid < 255) {
            int sh = m * 128 - 127 + tid;
            float f = 0.f;
            if (sh >= 0) {
                f = phi[sh * 24 + k];
                if (kv >= 24 && (sh & 1)) f = -f;
            }
            smem[tid] = f;
        }
        __syncthreads();
        bf16* Tp = Tb + (size_t)b3 * 16384;
#pragma unroll
        for (int it = 0; it < 8; ++it) {
            int q = it * 256 + tid;     // over 128 i x 16 j8
            int i = q >> 4, j8 = (q & 15) * 8;
            bf16x8 v;
#pragma unroll
            for (int jj = 0; jj < 8; ++jj)
                v[jj] = (bf16)smem[127 + i - (j8 + jj)];
            *(bf16x8*)(Tp + i * 128 + j8) = v;
        }
    }
}

// ---------------------------------------------------------------------------
// reduce: out = sum of 12 bf16 K-split partials, 8 outputs per thread
// ---------------------------------------------------------------------------
__global__ void reduce12(const bf16* __restrict__ P2, float* __restrict__ out) {
    int idx8 = blockIdx.x * 256 + threadIdx.x;   // over 2048*64
    if (idx8 >= 2048 * 64) return;
    size_t base = (size_t)idx8 * 8;
    float s[8];
#pragma unroll
    for (int jj = 0; jj < 8; ++jj) s[jj] = 0.f;
#pragma unroll
    for (int sp = 0; sp < 12; ++sp) {
        bf16x8 v = *(const bf16x8*)(P2 + (size_t)sp * 1048576 + base);
#pragma unroll
        for (int jj = 0; jj < 8; ++jj) s[jj] += (float)v[jj];
    }
#pragma unroll
    for (int jj = 0; jj < 8; ++jj) out[base + jj] = s[jj];
}

// ---------------------------------------------------------------------------
// Launch
// ---------------------------------------------------------------------------
extern "C" void kernel_launch(void* const* d_in, const int* in_sizes, int n_in,
                              void* d_out, int out_size, void* d_ws, size_t ws_size,
                              hipStream_t stream) {
    const float* x   = (const float*)d_in[0];
    const float* phi = (const float*)d_in[1];
    const float* M   = (const float*)d_in[2];
    const float* Mp  = (const float*)d_in[3];
    const float* Mm  = (const float*)d_in[4];
    float* out = (float*)d_out;
    char* ws = (char*)d_ws;

    // workspace layout (bytes)
    bf16* Tb = (bf16*)(ws + 0);           //  25,165,824  [48 x 16 x 128 x 128]
    bf16* xT = (bf16*)(ws + 25165824);    //   2,097,152
    bf16* A2 = (bf16*)(ws + 27262976);    // 106,954,752  [2048 x 26112]
    bf16* B2 = (bf16*)(ws + 134217728);   //  26,738,688  [ 512 x 26112]
    bf16* P2 = (bf16*)(ws + 160956416);   //  25,165,824  [12 x 2048 x 512] bf16
                                          //  total 186,122,240

    prep_all<<<6144, 256, 0, stream>>>(x, phi, M, Mp, Mm, xT, A2, B2, Tb);
    conv_gemm<<<3072, 256, 0, stream>>>(Tb, xT, A2);
    proj_gemm<<<dim3(16, 12, 4), 256, 0, stream>>>(A2, B2, P2);
    reduce12<<<512, 256, 0, stream>>>(P2, out);
}

// Round 14
// 301.407 us; speedup vs baseline: 1.1493x; 1.0232x over previous
//
#include <hip/hip_runtime.h>

typedef __bf16 bf16;
typedef bf16 bf16x8 __attribute__((ext_vector_type(8)));
typedef float floatx16 __attribute__((ext_vector_type(16)));

#define AS1 __attribute__((address_space(1)))
#define AS3 __attribute__((address_space(3)))

#define KTOT 26112   // A2/B2 leading dim: 48*512 spectral + 3*512 AR columns

// ---------------------------------------------------------------------------
// Tile engine: 128x128 block, 4 waves (2x2 of 64x64), BK=64, 32x32x16 bf16
// MFMA. Staging: global_load_lds width=16, lane-contiguous LDS, XOR swizzle
// on the global column. launch_bounds(256,4): 64 acc + <=64 arch VGPR ->
// 4 blocks/CU (R13 measured 72 arch -> 3 blocks/CU, the occupancy limiter).
// ---------------------------------------------------------------------------
__device__ __forceinline__ void stage_tile(const bf16* g, int ld, bf16* lds, int tid) {
#pragma unroll
    for (int it = 0; it < 4; ++it) {
        int q    = it * 256 + tid;        // 0..1023
        int row  = q >> 3;
        int col8 = (q & 7) ^ (row & 7);
        __builtin_amdgcn_global_load_lds(
            (const AS1 void*)(g + (size_t)row * ld + col8 * 8),
            (AS3 void*)(lds + q * 8), 16, 0, 0);
    }
}

// A frag (M=32,K=16): m=lane&31, k=8*(lane>>5)+j. B symmetric. 4 K-steps/BK.
__device__ __forceinline__ void mfma_block(const bf16* lA, const bf16* lB,
                                           floatx16 acc[2][2], int lane, int wm, int wn) {
    const int lrow = lane & 31;
    const int lk   = lane >> 5;
#pragma unroll
    for (int s = 0; s < 4; ++s) {   // four K=16 steps per BK=64
        bf16x8 af[2], bfr[2];
        const int c8 = s * 2 + lk;
#pragma unroll
        for (int mi = 0; mi < 2; ++mi) {
            int r = wm * 64 + mi * 32 + lrow;
            af[mi] = *(const bf16x8*)(lA + r * 64 + ((c8 ^ (r & 7)) << 3));
        }
#pragma unroll
        for (int ni = 0; ni < 2; ++ni) {
            int r = wn * 64 + ni * 32 + lrow;
            bfr[ni] = *(const bf16x8*)(lB + r * 64 + ((c8 ^ (r & 7)) << 3));
        }
#pragma unroll
        for (int mi = 0; mi < 2; ++mi)
#pragma unroll
            for (int ni = 0; ni < 2; ++ni)
                acc[mi][ni] = __builtin_amdgcn_mfma_f32_32x32x16_bf16(
                    af[mi], bfr[ni], acc[mi][ni], 0, 0, 0);
    }
}

// C/D mapping for 32x32 (m74/m101): col=lane&31, row=(r&3)+8*(r>>2)+4*(lane>>5)
#define CD_ROW(r, lane) (((r) & 3) + 8 * ((r) >> 2) + 4 * ((lane) >> 5))

// ---------------------------------------------------------------------------
// Conv phase: U2 tile per (kf, a, dblk). A = Tb[kf][a-c] (128x128 Toeplitz),
// B = xT rows d (2 MB total, L2-resident). C written bf16 straight into
// A2[t][kf*512 + dblk*128 + d]. Grid 3072, a-descending (LPT packing).
// ---------------------------------------------------------------------------
__global__ __launch_bounds__(256, 4) void conv_gemm(const bf16* __restrict__ Tb,
                                                    const bf16* __restrict__ xT,
                                                    bf16* __restrict__ A2) {
    __shared__ bf16 lA[128 * 64], lB[128 * 64];
    const int tid = threadIdx.x;
    const int lane = tid & 63, wave = tid >> 6, wm = wave & 1, wn = wave >> 1;
    const int bid = blockIdx.x;
    const int a    = 15 - (bid / 192);      // longest-first
    const int rem  = bid % 192;
    const int kf   = rem >> 2;
    const int dblk = rem & 3;

    floatx16 acc[2][2];
#pragma unroll
    for (int mi = 0; mi < 2; ++mi)
#pragma unroll
        for (int ni = 0; ni < 2; ++ni)
#pragma unroll
            for (int e = 0; e < 16; ++e) acc[mi][ni][e] = 0.f;

    for (int c = 0; c <= a; ++c) {
        const bf16* Ab = Tb + ((size_t)kf * 16 + (a - c)) * 16384;
        const bf16* Bb = xT + (size_t)(dblk * 128) * 2048 + c * 128;
#pragma unroll
        for (int kk = 0; kk < 128; kk += 64) {
            stage_tile(Ab + kk, 128, lA, tid);
            stage_tile(Bb + kk, 2048, lB, tid);
            __syncthreads();
            mfma_block(lA, lB, acc, lane, wm, wn);
            __syncthreads();
        }
    }
    bf16* Ob = A2 + (size_t)(a * 128) * KTOT + kf * 512 + dblk * 128;
#pragma unroll
    for (int mi = 0; mi < 2; ++mi)
#pragma unroll
        for (int ni = 0; ni < 2; ++ni)
#pragma unroll
            for (int r = 0; r < 16; ++r) {
                int row = wm * 64 + mi * 32 + CD_ROW(r, lane);
                int col = wn * 64 + ni * 32 + (lane & 31);
                Ob[(size_t)row * KTOT + col] = (bf16)acc[mi][ni][r];
            }
}

// ---------------------------------------------------------------------------
// Projection GEMM: out[t][o] = sum_K A2[t][K]*B2[o][K], K=26112 (408 BK).
// K-split x12 (K=2176 each) -> grid (16,12,4) = 768 = exactly 3 blocks/CU
// at 3/CU, 2 rounds exact at 4/CU (1024 slots) — either way no ragged tail.
// Partials in bf16 (quant error ~1-2 absolute, threshold 61).
// ---------------------------------------------------------------------------
__global__ __launch_bounds__(256, 4) void proj_gemm(const bf16* __restrict__ A2,
                                                    const bf16* __restrict__ B2,
                                                    bf16* __restrict__ P2) {
    __shared__ bf16 lA[128 * 64], lB[128 * 64];
    const int tid = threadIdx.x;
    const int lane = tid & 63, wave = tid >> 6, wm = wave & 1, wn = wave >> 1;
    const int bm = blockIdx.x, sp = blockIdx.y, bn = blockIdx.z;
    const bf16* Ab = A2 + (size_t)bm * 128 * KTOT + sp * 2176;
    const bf16* Bb = B2 + (size_t)bn * 128 * KTOT + sp * 2176;

    floatx16 acc[2][2];
#pragma unroll
    for (int mi = 0; mi < 2; ++mi)
#pragma unroll
        for (int ni = 0; ni < 2; ++ni)
#pragma unroll
            for (int e = 0; e < 16; ++e) acc[mi][ni][e] = 0.f;

    for (int kk = 0; kk < 2176; kk += 64) {
        stage_tile(Ab + kk, KTOT, lA, tid);
        stage_tile(Bb + kk, KTOT, lB, tid);
        __syncthreads();
        mfma_block(lA, lB, acc, lane, wm, wn);
        __syncthreads();
    }
    bf16* Pt = P2 + (size_t)sp * 1048576;
#pragma unroll
    for (int mi = 0; mi < 2; ++mi)
#pragma unroll
        for (int ni = 0; ni < 2; ++ni)
#pragma unroll
            for (int r = 0; r < 16; ++r) {
                int t = bm * 128 + wm * 64 + mi * 32 + CD_ROW(r, lane);
                int o = bn * 128 + wn * 64 + ni * 32 + (lane & 31);
                Pt[(size_t)t * 512 + o] = (bf16)acc[mi][ni][r];
            }
}

// ---------------------------------------------------------------------------
// Fused prep: xT transpose / A2-AR fill / B2 spectral transpose (vectorized
// bf16x8 stores) / B2-AR / Tb fill (LDS-staged phi)
// ---------------------------------------------------------------------------
__global__ void prep_all(const float* __restrict__ x, const float* __restrict__ phi,
                         const float* __restrict__ M, const float* __restrict__ Mp,
                         const float* __restrict__ Mm, bf16* __restrict__ xT,
                         bf16* __restrict__ A2, bf16* __restrict__ B2,
                         bf16* __restrict__ Tb) {
    __shared__ float smem[64 * 65];
    const int b = blockIdx.x, tid = threadIdx.x;
    if (b < 256) {
        // xT[d][t] = x[t][d], 64x64 LDS transpose tiles
        int tt = (b >> 3) * 64, dd = (b & 7) * 64;
#pragma unroll
        for (int it = 0; it < 16; ++it) {
            int q = it * 256 + tid;
            int r = q >> 6, cc = q & 63;
            smem[r * 65 + cc] = x[(size_t)(tt + r) * 512 + dd + cc];
        }
        __syncthreads();
#pragma unroll
        for (int it = 0; it < 16; ++it) {
            int q = it * 256 + tid;
            int r = q >> 6, cc = q & 63;
            xT[(size_t)(dd + r) * 2048 + tt + cc] = (bf16)smem[cc * 65 + r];
        }
    } else if (b < 1792) {
        // A2 AR columns: A2[t][24576 + i*512 + d] = x[t-i][d]
        int idx8 = (b - 256) * 256 + tid;   // over 2048*192
        int t = idx8 / 192, q = idx8 % 192;
        int i = q >> 6, d8 = (q & 63) * 8;
        bf16x8 v;
        if (t - i >= 0) {
            const float* xp = x + (size_t)(t - i) * 512 + d8;
#pragma unroll
            for (int jj = 0; jj < 8; ++jj) v[jj] = (bf16)xp[jj];
        } else {
#pragma unroll
            for (int jj = 0; jj < 8; ++jj) v[jj] = (bf16)0.f;
        }
        *(bf16x8*)(A2 + (size_t)t * KTOT + 24576 + i * 512 + d8) = v;
    } else if (b < 4864) {
        // B2[o][kv*512+d] = Mp/Mm[kv][d][o], 64x64 LDS transpose.
        // Store phase vectorized: bf16x8 per thread, 1 KB per wave-instr.
        int b2 = b - 1792;
        int kv = b2 >> 6, rem = b2 & 63;
        int dt = (rem >> 3) * 64, ot = (rem & 7) * 64;
        const float* src = (kv < 24) ? (Mp + (size_t)kv * 262144)
                                     : (Mm + (size_t)(kv - 24) * 262144);
#pragma unroll
        for (int it = 0; it < 16; ++it) {
            int q = it * 256 + tid;
            int r = q >> 6, cc = q & 63;   // r = d-local, cc = o-local
            smem[r * 65 + cc] = src[(size_t)(dt + r) * 512 + ot + cc];
        }
        __syncthreads();
#pragma unroll
        for (int it = 0; it < 2; ++it) {
            int q = it * 256 + tid;        // over 64 o x 8 d-chunks
            int o = q >> 3, d8 = (q & 7) * 8;
            bf16x8 v;
#pragma unroll
            for (int jj = 0; jj < 8; ++jj)
                v[jj] = (bf16)smem[(d8 + jj) * 65 + o];
            *(bf16x8*)(B2 + (size_t)(ot + o) * KTOT + kv * 512 + dt + d8) = v;
        }
    } else if (b < 5376) {
        // B2 AR columns: B2[o][24576 + i*512 + d] = M[o][d][i]
        int o = b - 4864;
        for (int q = tid; q < 1536; q += 256) smem[q] = M[(size_t)o * 1536 + q];
        __syncthreads();
        for (int q = tid; q < 1536; q += 256) {
            int i = q >> 9, d = q & 511;
            B2[(size_t)o * KTOT + 24576 + q] = (bf16)smem[d * 3 + i];
        }
    } else {
        // Tb fill, one block per (kv,m): Tb[kv][m][i][j] = phi_kv[m*128+i-j].
        int b3 = b - 5376;              // 0..767
        int kv = b3 >> 4, m = b3 & 15;
        int k  = (kv >= 24) ? kv - 24 : kv;
        if (tid < 255) {
            int sh = m * 128 - 127 + tid;
            float f = 0.f;
            if (sh >= 0) {
                f = phi[sh * 24 + k];
                if (kv >= 24 && (sh & 1)) f = -f;
            }
            smem[tid] = f;
        }
        __syncthreads();
        bf16* Tp = Tb + (size_t)b3 * 16384;
#pragma unroll
        for (int it = 0; it < 8; ++it) {
            int q = it * 256 + tid;     // over 128 i x 16 j8
            int i = q >> 4, j8 = (q & 15) * 8;
            bf16x8 v;
#pragma unroll
            for (int jj = 0; jj < 8; ++jj)
                v[jj] = (bf16)smem[127 + i - (j8 + jj)];
            *(bf16x8*)(Tp + i * 128 + j8) = v;
        }
    }
}

// ---------------------------------------------------------------------------
// reduce: out = sum of 12 bf16 K-split partials, 8 outputs per thread
// ---------------------------------------------------------------------------
__global__ void reduce12(const bf16* __restrict__ P2, float* __restrict__ out) {
    int idx8 = blockIdx.x * 256 + threadIdx.x;   // over 2048*64
    if (idx8 >= 2048 * 64) return;
    size_t base = (size_t)idx8 * 8;
    float s[8];
#pragma unroll
    for (int jj = 0; jj < 8; ++jj) s[jj] = 0.f;
#pragma unroll
    for (int sp = 0; sp < 12; ++sp) {
        bf16x8 v = *(const bf16x8*)(P2 + (size_t)sp * 1048576 + base);
#pragma unroll
        for (int jj = 0; jj < 8; ++jj) s[jj] += (float)v[jj];
    }
#pragma unroll
    for (int jj = 0; jj < 8; ++jj) out[base + jj] = s[jj];
}

// ---------------------------------------------------------------------------
// Launch
// ---------------------------------------------------------------------------
extern "C" void kernel_launch(void* const* d_in, const int* in_sizes, int n_in,
                              void* d_out, int out_size, void* d_ws, size_t ws_size,
                              hipStream_t stream) {
    const float* x   = (const float*)d_in[0];
    const float* phi = (const float*)d_in[1];
    const float* M   = (const float*)d_in[2];
    const float* Mp  = (const float*)d_in[3];
    const float* Mm  = (const float*)d_in[4];
    float* out = (float*)d_out;
    char* ws = (char*)d_ws;

    // workspace layout (bytes)
    bf16* Tb = (bf16*)(ws + 0);           //  25,165,824  [48 x 16 x 128 x 128]
    bf16* xT = (bf16*)(ws + 25165824);    //   2,097,152
    bf16* A2 = (bf16*)(ws + 27262976);    // 106,954,752  [2048 x 26112]
    bf16* B2 = (bf16*)(ws + 134217728);   //  26,738,688  [ 512 x 26112]
    bf16* P2 = (bf16*)(ws + 160956416);   //  25,165,824  [12 x 2048 x 512] bf16
                                          //  total 186,122,240

    prep_all<<<6144, 256, 0, stream>>>(x, phi, M, Mp, Mm, xT, A2, B2, Tb);
    conv_gemm<<<3072, 256, 0, stream>>>(Tb, xT, A2);
    proj_gemm<<<dim3(16, 12, 4), 256, 0, stream>>>(A2, B2, P2);
    reduce12<<<512, 256, 0, stream>>>(P2, out);
}